// Round 4
// baseline (780.025 us; speedup 1.0000x reference)
//
#include <hip/hip_runtime.h>
#include <hip/hip_bf16.h>

// GCNConv encoder, CSR-gather formulation (no fp32 global atomics):
//   cnt[d]   = #edges with dst==d                      (int atomics)
//   cursor   = exclusive_prefix_sum(cnt)               (2-level scan)
//   fill: srcs[cursor[dst]++] = src                    (int atomics; after, cursor[d]=row end)
//   dinv[i]  = rsqrt(cnt[i]+1)                         (self-loop degree)
//   h = x @ W  (fp32 compute, stored bf16)             (register-tiled LDS GEMM)
//   out[d][j] = h[d][j]*dinv[d]^2 + b[j] + sum_p h[srcs[p]][j]*dinv[srcs[p]]*dinv[d]
//
// ws: dinv[n] f32 | cnt[n] i32 | cursor[n] i32 | bsum[128] i32 | h[n*32] bf16 | srcs[E] i32
//     = 15.6 MB. Fallback (atomic scatter, 7.2 MB) if ws_size too small.

#define LATD 32
#define INCH 128

// ---------------- GEMM: h = x @ W, [n,128]@[128,32] -> bf16 [n,32] ----------------
// 128 threads, 64 rows/block, 4 rows x 4 cols per thread, b128 LDS reads.
__global__ __launch_bounds__(128) void gemm_tile_k(const float* __restrict__ x,
                                                   const float* __restrict__ W,
                                                   __hip_bfloat16* __restrict__ h, int n) {
    __shared__ float xs[64][132];     // pad 132: 16B-aligned rows (528B), tolerable 4-way
    __shared__ float Wl[INCH][LATD];  // 16 KiB, conflict-free reads
    int tid = threadIdx.x;
    {
        const float4* Wv = (const float4*)W;
        float4* Wlv = (float4*)&Wl[0][0];
#pragma unroll
        for (int i = 0; i < 8; ++i) Wlv[tid + 128 * i] = Wv[tid + 128 * i];
    }
    int row0 = blockIdx.x * 64;
#pragma unroll
    for (int v = tid; v < 64 * 32; v += 128) {
        int r = v >> 5, kc = v & 31;
        int gr = row0 + r;
        float4 val = make_float4(0.f, 0.f, 0.f, 0.f);
        if (gr < n) val = ((const float4*)(x + (size_t)gr * INCH))[kc];
        *(float4*)&xs[r][kc * 4] = val;
    }
    __syncthreads();
    int c = tid & 7, rr = tid >> 3;
    int j0 = c * 4, r0 = rr * 4;
    float acc[4][4] = {};
#pragma unroll
    for (int kk = 0; kk < INCH; kk += 4) {
        float4 w0 = *(const float4*)&Wl[kk + 0][j0];
        float4 w1 = *(const float4*)&Wl[kk + 1][j0];
        float4 w2 = *(const float4*)&Wl[kk + 2][j0];
        float4 w3 = *(const float4*)&Wl[kk + 3][j0];
#pragma unroll
        for (int ri = 0; ri < 4; ++ri) {
            float4 a = *(const float4*)&xs[r0 + ri][kk];
            acc[ri][0] += a.x * w0.x + a.y * w1.x + a.z * w2.x + a.w * w3.x;
            acc[ri][1] += a.x * w0.y + a.y * w1.y + a.z * w2.y + a.w * w3.y;
            acc[ri][2] += a.x * w0.z + a.y * w1.z + a.z * w2.z + a.w * w3.z;
            acc[ri][3] += a.x * w0.w + a.y * w1.w + a.z * w2.w + a.w * w3.w;
        }
    }
#pragma unroll
    for (int ri = 0; ri < 4; ++ri) {
        int gr = row0 + r0 + ri;
        if (gr < n) {
#pragma unroll
            for (int cj = 0; cj < 4; ++cj)
                h[(size_t)gr * LATD + j0 + cj] = __float2bfloat16(acc[ri][cj]);
        }
    }
}

// ---------------- CSR build ----------------
__global__ void zero_cnt_k(int* cnt, int n) {
    int i = blockIdx.x * 256 + threadIdx.x;
    if (i < n) cnt[i] = 0;
}

__global__ void count_k(const int* __restrict__ ei, const int* __restrict__ yei,
                        int* __restrict__ cnt, int e1, int e2) {
    int e = blockIdx.x * 256 + threadIdx.x;
    if (e >= e1 + e2) return;
    int dst = (e < e1) ? ei[e1 + e] : yei[e2 + (e - e1)];
    atomicAdd(&cnt[dst], 1);
}

// 1024 items/block exclusive scan, stage 1: per-element local exclusive + block totals
__global__ __launch_bounds__(256) void scan1_k(const int* __restrict__ cnt, int* __restrict__ cursor,
                                               int* __restrict__ bsum, int n) {
    __shared__ int sd[256];
    int tid = threadIdx.x;
    int base = blockIdx.x * 1024 + tid * 4;
    int v0 = (base + 0 < n) ? cnt[base + 0] : 0;
    int v1 = (base + 1 < n) ? cnt[base + 1] : 0;
    int v2 = (base + 2 < n) ? cnt[base + 2] : 0;
    int v3 = (base + 3 < n) ? cnt[base + 3] : 0;
    int p1 = v0, p2 = v0 + v1, p3 = v0 + v1 + v2, tot = p3 + v3;
    sd[tid] = tot;
    __syncthreads();
    int val = tot;
    for (int off = 1; off < 256; off <<= 1) {
        int t = (tid >= off) ? sd[tid - off] : 0;
        __syncthreads();
        val += t;
        sd[tid] = val;
        __syncthreads();
    }
    int ebase = val - tot;  // exclusive base for this thread's 4 items
    if (base + 0 < n) cursor[base + 0] = ebase;
    if (base + 1 < n) cursor[base + 1] = ebase + p1;
    if (base + 2 < n) cursor[base + 2] = ebase + p2;
    if (base + 3 < n) cursor[base + 3] = ebase + p3;
    if (tid == 255) bsum[blockIdx.x] = val;  // block total (inclusive of all 1024)
}

// stage 2: exclusive scan of <=128 block totals, single block
__global__ __launch_bounds__(128) void scan2_k(int* bsum, int nb) {
    __shared__ int sd[128];
    int tid = threadIdx.x;
    int v = (tid < nb) ? bsum[tid] : 0;
    sd[tid] = v;
    __syncthreads();
    int val = v;
    for (int off = 1; off < 128; off <<= 1) {
        int t = (tid >= off) ? sd[tid - off] : 0;
        __syncthreads();
        val += t;
        sd[tid] = val;
        __syncthreads();
    }
    if (tid < nb) bsum[tid] = val - v;  // exclusive
}

// stage 3: add block offsets; also dinv = rsqrt(cnt+1)
__global__ void scan3_k(int* __restrict__ cursor, const int* __restrict__ bsum,
                        const int* __restrict__ cnt, float* __restrict__ dinv, int n) {
    int i = blockIdx.x * 256 + threadIdx.x;
    if (i >= n) return;
    cursor[i] += bsum[i >> 10];
    dinv[i] = rsqrtf((float)cnt[i] + 1.0f);
}

__global__ void fill_k(const int* __restrict__ ei, const int* __restrict__ yei,
                       int* __restrict__ cursor, int* __restrict__ srcs, int e1, int e2) {
    int e = blockIdx.x * 256 + threadIdx.x;
    if (e >= e1 + e2) return;
    int src, dst;
    if (e < e1) { src = ei[e]; dst = ei[e1 + e]; }
    else        { int t = e - e1; src = yei[t]; dst = yei[e2 + t]; }
    int pos = atomicAdd(&cursor[dst], 1);
    srcs[pos] = src;
}

// ---------------- gather: 32 lanes per dst node, register accumulation ----------------
__global__ __launch_bounds__(256) void gather_k(const int* __restrict__ cursor,
                                                const int* __restrict__ cnt,
                                                const float* __restrict__ dinv,
                                                const __hip_bfloat16* __restrict__ h,
                                                const int* __restrict__ srcs,
                                                const float* __restrict__ b,
                                                float* __restrict__ out, int n) {
    int node = blockIdx.x * 8 + (threadIdx.x >> 5);
    if (node >= n) return;
    int j = threadIdx.x & 31;
    int end = cursor[node];            // after fill, cursor[d] = row end
    int start = end - cnt[node];
    float dv = dinv[node];
    float acc = __bfloat162float(h[(size_t)node * LATD + j]) * dv * dv + b[j];  // self-loop + bias
    for (int p = start; p < end; ++p) {
        int s = srcs[p];                            // broadcast within 32-lane group
        float nrm = dinv[s] * dv;                   // broadcast
        acc += __bfloat162float(h[(size_t)s * LATD + j]) * nrm;  // coalesced 64B row
    }
    out[(size_t)node * LATD + j] = acc;
}

// ---------------- fallback path (atomic scatter), used only if ws too small ----------------
__global__ void dinv_k(const int* __restrict__ cnt, float* __restrict__ dinv, int n) {
    int i = blockIdx.x * 256 + threadIdx.x;
    if (i < n) dinv[i] = rsqrtf((float)cnt[i] + 1.0f);
}

__global__ void selfbias_k(const float* __restrict__ dinv, const __hip_bfloat16* __restrict__ h,
                           const float* __restrict__ b, float* __restrict__ out, int total) {
    int idx = blockIdx.x * 256 + threadIdx.x;
    if (idx >= total) return;
    int i = idx >> 5, j = idx & 31;
    float d = dinv[i];
    out[idx] = __bfloat162float(h[idx]) * d * d + b[j];
}

__global__ void scatter_atomic_k(const int* __restrict__ ei, const int* __restrict__ yei,
                                 const float* __restrict__ dinv, const __hip_bfloat16* __restrict__ h,
                                 float* __restrict__ out, int e1, int e2) {
    int idx = blockIdx.x * 256 + threadIdx.x;
    int e = idx >> 5;
    if (e >= e1 + e2) return;
    int j = idx & 31;
    int src, dst;
    if (e < e1) { src = ei[e]; dst = ei[e1 + e]; }
    else        { int t = e - e1; src = yei[t]; dst = yei[e2 + t]; }
    float norm = dinv[src] * dinv[dst];
    atomicAdd(&out[(size_t)dst * LATD + j], __bfloat162float(h[(size_t)src * LATD + j]) * norm);
}

static inline size_t aln(size_t x) { return (x + 15) & ~(size_t)15; }

extern "C" void kernel_launch(void* const* d_in, const int* in_sizes, int n_in,
                              void* d_out, int out_size, void* d_ws, size_t ws_size,
                              hipStream_t stream) {
    const float* x  = (const float*)d_in[0];
    const int* ei   = (const int*)d_in[1];
    const int* yei  = (const int*)d_in[2];
    const float* W  = (const float*)d_in[3];
    const float* b  = (const float*)d_in[4];
    float* out = (float*)d_out;

    int n  = in_sizes[0] / INCH;
    int e1 = in_sizes[1] / 2;
    int e2 = in_sizes[2] / 2;
    int E  = e1 + e2;

    char* p = (char*)d_ws;
    size_t off = 0;
    float* dinv  = (float*)(p + off); off += aln((size_t)n * 4);
    int*   cnt   = (int*)(p + off);   off += aln((size_t)n * 4);
    int*   cursor= (int*)(p + off);   off += aln((size_t)n * 4);
    int*   bsum  = (int*)(p + off);   off += aln(128 * 4);
    __hip_bfloat16* h = (__hip_bfloat16*)(p + off); off += aln((size_t)n * LATD * 2);
    int*   srcs  = (int*)(p + off);   off += aln((size_t)E * 4);
    bool csr_ok = (off <= ws_size);

    int gb_n   = (n + 255) / 256;
    int gb_e   = (E + 255) / 256;
    int nb     = (n + 1023) / 1024;   // <=128 for n<=131072

    // common: h = x @ W (bf16 out), cnt = dst histogram
    gemm_tile_k<<<(n + 63) / 64, 128, 0, stream>>>(x, W, h, n);
    zero_cnt_k<<<gb_n, 256, 0, stream>>>(cnt, n);
    count_k<<<gb_e, 256, 0, stream>>>(ei, yei, cnt, e1, e2);

    if (csr_ok) {
        scan1_k<<<nb, 256, 0, stream>>>(cnt, cursor, bsum, n);
        scan2_k<<<1, 128, 0, stream>>>(bsum, nb);
        scan3_k<<<gb_n, 256, 0, stream>>>(cursor, bsum, cnt, dinv, n);
        fill_k<<<gb_e, 256, 0, stream>>>(ei, yei, cursor, srcs, e1, e2);
        gather_k<<<(n + 7) / 8, 256, 0, stream>>>(cursor, cnt, dinv, h, srcs, b, out, n);
    } else {
        dinv_k<<<gb_n, 256, 0, stream>>>(cnt, dinv, n);
        selfbias_k<<<(out_size + 255) / 256, 256, 0, stream>>>(dinv, h, b, out, out_size);
        scatter_atomic_k<<<((size_t)E * LATD + 255) / 256, 256, 0, stream>>>(ei, yei, dinv, h, out, e1, e2);
    }
}

// Round 5
// 445.709 us; speedup vs baseline: 1.7501x; 1.7501x over previous
//
#include <hip/hip_runtime.h>
#include <hip/hip_bf16.h>

// GCNConv encoder, CSR-gather formulation (no fp32 global atomics):
//   cnt[d]   = #edges with dst==d                      (int atomics)
//   cursor   = exclusive_prefix_sum(cnt)               (2-level scan)
//   fill: srcs[cursor[dst]++] = src                    (int atomics; after, cursor[d]=row end)
//   dinv[i]  = rsqrt(cnt[i]+1)                         (self-loop degree)
//   h = x @ W  (fp32 compute, stored bf16)             (register-tiled LDS GEMM, unroll-capped)
//   out[d][j] = h[d][j]*dinv[d]^2 + b[j] + dinv[d]*sum_p h[srcs[p]][j]*dinv[srcs[p]]
//
// ws: dinv[n] f32 | cnt[n] i32 | cursor[n] i32 | bsum[128] i32 | h[n*32] bf16 | srcs[E] i32
//     = 15.6 MB. Fallback (atomic scatter) if ws_size too small.

#define LATD 32
#define INCH 128

// ---------------- GEMM: h = x @ W, [n,128]@[128,32] -> bf16 [n,32] ----------------
// 128 threads, 64 rows/block, 4 rows x 4 cols per thread, b128 LDS reads.
// unroll capped to avoid the round-4 256-VGPR spill (1 GB scratch traffic).
__global__ __launch_bounds__(128) void gemm_tile_k(const float* __restrict__ x,
                                                   const float* __restrict__ W,
                                                   __hip_bfloat16* __restrict__ h, int n) {
    __shared__ float xs[64][132];     // 132: keeps float4 alignment, breaks pow-2 stride
    __shared__ float Wl[INCH][LATD];  // 16 KiB, conflict-free float4 reads
    int tid = threadIdx.x;
    {
        const float4* Wv = (const float4*)W;
        float4* Wlv = (float4*)&Wl[0][0];
#pragma unroll 2
        for (int i = 0; i < 8; ++i) Wlv[tid + 128 * i] = Wv[tid + 128 * i];
    }
    int row0 = blockIdx.x * 64;
#pragma unroll 4
    for (int v = tid; v < 64 * 32; v += 128) {
        int r = v >> 5, kc = v & 31;
        int gr = row0 + r;
        float4 val = make_float4(0.f, 0.f, 0.f, 0.f);
        if (gr < n) val = ((const float4*)(x + (size_t)gr * INCH))[kc];
        *(float4*)&xs[r][kc * 4] = val;
    }
    __syncthreads();
    int c = tid & 7, rr = tid >> 3;
    int j0 = c * 4, r0 = rr * 4;
    float acc[4][4] = {};
#pragma unroll 2
    for (int kk = 0; kk < INCH; kk += 4) {
        float4 w0 = *(const float4*)&Wl[kk + 0][j0];
        float4 w1 = *(const float4*)&Wl[kk + 1][j0];
        float4 w2 = *(const float4*)&Wl[kk + 2][j0];
        float4 w3 = *(const float4*)&Wl[kk + 3][j0];
#pragma unroll
        for (int ri = 0; ri < 4; ++ri) {
            float4 a = *(const float4*)&xs[r0 + ri][kk];
            acc[ri][0] += a.x * w0.x + a.y * w1.x + a.z * w2.x + a.w * w3.x;
            acc[ri][1] += a.x * w0.y + a.y * w1.y + a.z * w2.y + a.w * w3.y;
            acc[ri][2] += a.x * w0.z + a.y * w1.z + a.z * w2.z + a.w * w3.z;
            acc[ri][3] += a.x * w0.w + a.y * w1.w + a.z * w2.w + a.w * w3.w;
        }
    }
#pragma unroll
    for (int ri = 0; ri < 4; ++ri) {
        int gr = row0 + r0 + ri;
        if (gr < n) {
            __hip_bfloat16 tmp[4];
#pragma unroll
            for (int cj = 0; cj < 4; ++cj) tmp[cj] = __float2bfloat16(acc[ri][cj]);
            *(ushort4*)(&h[(size_t)gr * LATD + j0]) = *(const ushort4*)tmp;  // packed 8B store
        }
    }
}

// ---------------- CSR build ----------------
__global__ void zero_cnt_k(int* cnt, int n) {
    int i = blockIdx.x * 256 + threadIdx.x;
    if (i < n) cnt[i] = 0;
}

__global__ void count_k(const int* __restrict__ ei, const int* __restrict__ yei,
                        int* __restrict__ cnt, int e1, int e2) {
    int e = blockIdx.x * 256 + threadIdx.x;
    if (e >= e1 + e2) return;
    int dst = (e < e1) ? ei[e1 + e] : yei[e2 + (e - e1)];
    atomicAdd(&cnt[dst], 1);
}

__global__ __launch_bounds__(256) void scan1_k(const int* __restrict__ cnt, int* __restrict__ cursor,
                                               int* __restrict__ bsum, int n) {
    __shared__ int sd[256];
    int tid = threadIdx.x;
    int base = blockIdx.x * 1024 + tid * 4;
    int v0 = (base + 0 < n) ? cnt[base + 0] : 0;
    int v1 = (base + 1 < n) ? cnt[base + 1] : 0;
    int v2 = (base + 2 < n) ? cnt[base + 2] : 0;
    int v3 = (base + 3 < n) ? cnt[base + 3] : 0;
    int p1 = v0, p2 = v0 + v1, p3 = v0 + v1 + v2, tot = p3 + v3;
    sd[tid] = tot;
    __syncthreads();
    int val = tot;
    for (int off = 1; off < 256; off <<= 1) {
        int t = (tid >= off) ? sd[tid - off] : 0;
        __syncthreads();
        val += t;
        sd[tid] = val;
        __syncthreads();
    }
    int ebase = val - tot;
    if (base + 0 < n) cursor[base + 0] = ebase;
    if (base + 1 < n) cursor[base + 1] = ebase + p1;
    if (base + 2 < n) cursor[base + 2] = ebase + p2;
    if (base + 3 < n) cursor[base + 3] = ebase + p3;
    if (tid == 255) bsum[blockIdx.x] = val;
}

__global__ __launch_bounds__(128) void scan2_k(int* bsum, int nb) {
    __shared__ int sd[128];
    int tid = threadIdx.x;
    int v = (tid < nb) ? bsum[tid] : 0;
    sd[tid] = v;
    __syncthreads();
    int val = v;
    for (int off = 1; off < 128; off <<= 1) {
        int t = (tid >= off) ? sd[tid - off] : 0;
        __syncthreads();
        val += t;
        sd[tid] = val;
        __syncthreads();
    }
    if (tid < nb) bsum[tid] = val - v;
}

__global__ void scan3_k(int* __restrict__ cursor, const int* __restrict__ bsum,
                        const int* __restrict__ cnt, float* __restrict__ dinv, int n) {
    int i = blockIdx.x * 256 + threadIdx.x;
    if (i >= n) return;
    cursor[i] += bsum[i >> 10];
    dinv[i] = rsqrtf((float)cnt[i] + 1.0f);
}

__global__ void fill_k(const int* __restrict__ ei, const int* __restrict__ yei,
                       int* __restrict__ cursor, int* __restrict__ srcs, int e1, int e2) {
    int e = blockIdx.x * 256 + threadIdx.x;
    if (e >= e1 + e2) return;
    int src, dst;
    if (e < e1) { src = ei[e]; dst = ei[e1 + e]; }
    else        { int t = e - e1; src = yei[t]; dst = yei[e2 + t]; }
    int pos = atomicAdd(&cursor[dst], 1);
    srcs[pos] = src;
}

// ---------------- gather: 32 lanes per dst node, shuffle-broadcast edge metadata ----------------
__global__ __launch_bounds__(256) void gather_k(const int* __restrict__ cursor,
                                                const int* __restrict__ cnt,
                                                const float* __restrict__ dinv,
                                                const __hip_bfloat16* __restrict__ h,
                                                const int* __restrict__ srcs,
                                                const float* __restrict__ b,
                                                float* __restrict__ out, int n) {
    int node = blockIdx.x * 8 + (threadIdx.x >> 5);
    if (node >= n) return;
    int j = threadIdx.x & 31;
    int end = cursor[node];            // after fill, cursor[d] = row end
    int start = end - cnt[node];
    float dv = dinv[node];
    float accn = 0.0f;                 // sum over neighbors of h[s][j]*dinv[s]
    for (int base = start; base < end; base += 32) {
        int m = end - base; if (m > 32) m = 32;
        // lane-parallel: one coalesced srcs load + one dinv gather per 32 edges
        int   myS = (j < m) ? srcs[base + j] : 0;
        float myW = (j < m) ? dinv[myS] : 0.0f;
        if (m == 32) {
#pragma unroll
            for (int t = 0; t < 32; ++t) {
                int   s = __shfl(myS, t, 32);
                float w = __shfl(myW, t, 32);
                accn += __bfloat162float(h[(size_t)s * LATD + j]) * w;
            }
        } else {
#pragma unroll 4
            for (int t = 0; t < m; ++t) {
                int   s = __shfl(myS, t, 32);
                float w = __shfl(myW, t, 32);
                accn += __bfloat162float(h[(size_t)s * LATD + j]) * w;
            }
        }
    }
    float self = __bfloat162float(h[(size_t)node * LATD + j]);
    out[(size_t)node * LATD + j] = self * dv * dv + b[j] + accn * dv;
}

// ---------------- fallback path (atomic scatter), used only if ws too small ----------------
__global__ void dinv_k(const int* __restrict__ cnt, float* __restrict__ dinv, int n) {
    int i = blockIdx.x * 256 + threadIdx.x;
    if (i < n) dinv[i] = rsqrtf((float)cnt[i] + 1.0f);
}

__global__ void selfbias_k(const float* __restrict__ dinv, const __hip_bfloat16* __restrict__ h,
                           const float* __restrict__ b, float* __restrict__ out, int total) {
    int idx = blockIdx.x * 256 + threadIdx.x;
    if (idx >= total) return;
    int i = idx >> 5, j = idx & 31;
    float d = dinv[i];
    out[idx] = __bfloat162float(h[idx]) * d * d + b[j];
}

__global__ void scatter_atomic_k(const int* __restrict__ ei, const int* __restrict__ yei,
                                 const float* __restrict__ dinv, const __hip_bfloat16* __restrict__ h,
                                 float* __restrict__ out, int e1, int e2) {
    int idx = blockIdx.x * 256 + threadIdx.x;
    int e = idx >> 5;
    if (e >= e1 + e2) return;
    int j = idx & 31;
    int src, dst;
    if (e < e1) { src = ei[e]; dst = ei[e1 + e]; }
    else        { int t = e - e1; src = yei[t]; dst = yei[e2 + t]; }
    float norm = dinv[src] * dinv[dst];
    atomicAdd(&out[(size_t)dst * LATD + j], __bfloat162float(h[(size_t)src * LATD + j]) * norm);
}

static inline size_t aln(size_t x) { return (x + 15) & ~(size_t)15; }

extern "C" void kernel_launch(void* const* d_in, const int* in_sizes, int n_in,
                              void* d_out, int out_size, void* d_ws, size_t ws_size,
                              hipStream_t stream) {
    const float* x  = (const float*)d_in[0];
    const int* ei   = (const int*)d_in[1];
    const int* yei  = (const int*)d_in[2];
    const float* W  = (const float*)d_in[3];
    const float* b  = (const float*)d_in[4];
    float* out = (float*)d_out;

    int n  = in_sizes[0] / INCH;
    int e1 = in_sizes[1] / 2;
    int e2 = in_sizes[2] / 2;
    int E  = e1 + e2;

    char* p = (char*)d_ws;
    size_t off = 0;
    float* dinv  = (float*)(p + off); off += aln((size_t)n * 4);
    int*   cnt   = (int*)(p + off);   off += aln((size_t)n * 4);
    int*   cursor= (int*)(p + off);   off += aln((size_t)n * 4);
    int*   bsum  = (int*)(p + off);   off += aln(128 * 4);
    __hip_bfloat16* h = (__hip_bfloat16*)(p + off); off += aln((size_t)n * LATD * 2);
    int*   srcs  = (int*)(p + off);   off += aln((size_t)E * 4);
    bool csr_ok = (off <= ws_size);

    int gb_n = (n + 255) / 256;
    int gb_e = (E + 255) / 256;
    int nb   = (n + 1023) / 1024;   // <=128 for n<=131072

    gemm_tile_k<<<(n + 63) / 64, 128, 0, stream>>>(x, W, h, n);
    zero_cnt_k<<<gb_n, 256, 0, stream>>>(cnt, n);
    count_k<<<gb_e, 256, 0, stream>>>(ei, yei, cnt, e1, e2);

    if (csr_ok) {
        scan1_k<<<nb, 256, 0, stream>>>(cnt, cursor, bsum, n);
        scan2_k<<<1, 128, 0, stream>>>(bsum, nb);
        scan3_k<<<gb_n, 256, 0, stream>>>(cursor, bsum, cnt, dinv, n);
        fill_k<<<gb_e, 256, 0, stream>>>(ei, yei, cursor, srcs, e1, e2);
        gather_k<<<(n + 7) / 8, 256, 0, stream>>>(cursor, cnt, dinv, h, srcs, b, out, n);
    } else {
        dinv_k<<<gb_n, 256, 0, stream>>>(cnt, dinv, n);
        selfbias_k<<<(out_size + 255) / 256, 256, 0, stream>>>(dinv, h, b, out, out_size);
        scatter_atomic_k<<<((size_t)E * LATD + 255) / 256, 256, 0, stream>>>(ei, yei, dinv, h, out, e1, e2);
    }
}

// Round 6
// 330.938 us; speedup vs baseline: 2.3570x; 1.3468x over previous
//
#include <hip/hip_runtime.h>
#include <hip/hip_bf16.h>

// GCNConv encoder — LDS-multisplit CSR build + fused gather.
//   bucket(dst) = dst>>7  (128 dst-values per bucket, NB = ceil(n/128) <= 1024)
//   A-count:   per-block LDS hist -> global btot
//   scan:      bstart = excl_scan(btot); bcursor = bstart
//   A-scatter: per 8192-edge block: LDS hist+scan, reserve segment per bucket
//              (atomicAdd bcursor), reorder packed (src<<7|ldst) in LDS, coalesced copy-out
//   B1:        per-bucket local hist -> dinv = rsqrt(deg+1)
//   B2:        per-bucket: rebuild local CSR in LDS, gather h rows + write out (fused)
//   out[d][j] = h[d][j]*dinv[d]^2 + b[j] + dinv[d] * sum_src h[src][j]*dinv[src]
//
// ws: dinv[n] f32 | h[n*32] bf16 | bucketed[E] u32 | btot/bstart/bcursor[1024] i32  ~= 14.9 MB
// Fallback (atomic scatter) if ws too small or NB > 1024.

#define LATD 32
#define INCH 128
#define BSH 7              // bucket shift
#define BW 128             // dst values per bucket
#define ACHUNK 8192        // edges per pass-A block
#define BCAP 4096          // pass-B LDS edge capacity per chunk

__device__ __forceinline__ void load_edge(const int* __restrict__ ei, const int* __restrict__ yei,
                                          int e1, int e2, int e, int& src, int& dst) {
    if (e < e1) { src = ei[e]; dst = ei[e1 + e]; }
    else        { int t = e - e1; src = yei[t]; dst = yei[e2 + t]; }
}

// ---------------- GEMM: h = x @ W -> bf16 [n,32] (proven round-5 version) ----------------
__global__ __launch_bounds__(128) void gemm_tile_k(const float* __restrict__ x,
                                                   const float* __restrict__ W,
                                                   __hip_bfloat16* __restrict__ h, int n) {
    __shared__ float xs[64][132];
    __shared__ float Wl[INCH][LATD];
    int tid = threadIdx.x;
    {
        const float4* Wv = (const float4*)W;
        float4* Wlv = (float4*)&Wl[0][0];
#pragma unroll 2
        for (int i = 0; i < 8; ++i) Wlv[tid + 128 * i] = Wv[tid + 128 * i];
    }
    int row0 = blockIdx.x * 64;
#pragma unroll 4
    for (int v = tid; v < 64 * 32; v += 128) {
        int r = v >> 5, kc = v & 31;
        int gr = row0 + r;
        float4 val = make_float4(0.f, 0.f, 0.f, 0.f);
        if (gr < n) val = ((const float4*)(x + (size_t)gr * INCH))[kc];
        *(float4*)&xs[r][kc * 4] = val;
    }
    __syncthreads();
    int c = tid & 7, rr = tid >> 3;
    int j0 = c * 4, r0 = rr * 4;
    float acc[4][4] = {};
#pragma unroll 2
    for (int kk = 0; kk < INCH; kk += 4) {
        float4 w0 = *(const float4*)&Wl[kk + 0][j0];
        float4 w1 = *(const float4*)&Wl[kk + 1][j0];
        float4 w2 = *(const float4*)&Wl[kk + 2][j0];
        float4 w3 = *(const float4*)&Wl[kk + 3][j0];
#pragma unroll
        for (int ri = 0; ri < 4; ++ri) {
            float4 a = *(const float4*)&xs[r0 + ri][kk];
            acc[ri][0] += a.x * w0.x + a.y * w1.x + a.z * w2.x + a.w * w3.x;
            acc[ri][1] += a.x * w0.y + a.y * w1.y + a.z * w2.y + a.w * w3.y;
            acc[ri][2] += a.x * w0.z + a.y * w1.z + a.z * w2.z + a.w * w3.z;
            acc[ri][3] += a.x * w0.w + a.y * w1.w + a.z * w2.w + a.w * w3.w;
        }
    }
#pragma unroll
    for (int ri = 0; ri < 4; ++ri) {
        int gr = row0 + r0 + ri;
        if (gr < n) {
            __hip_bfloat16 tmp[4];
#pragma unroll
            for (int cj = 0; cj < 4; ++cj) tmp[cj] = __float2bfloat16(acc[ri][cj]);
            *(ushort4*)(&h[(size_t)gr * LATD + j0]) = *(const ushort4*)tmp;
        }
    }
}

// ---------------- misc ----------------
__global__ void zero_i32_k(int* p, int cnt) {
    int i = blockIdx.x * 256 + threadIdx.x;
    if (i < cnt) p[i] = 0;
}

// ---------------- pass A-count: bucket histogram ----------------
__global__ __launch_bounds__(256) void bucket_count_k(const int* __restrict__ ei, const int* __restrict__ yei,
                                                      int e1, int e2, int* __restrict__ btot, int NB) {
    __shared__ int hist[1024];
    int tid = threadIdx.x;
    for (int i = tid; i < NB; i += 256) hist[i] = 0;
    __syncthreads();
    int E = e1 + e2;
    int e0 = blockIdx.x * ACHUNK;
    int m = E - e0; if (m > ACHUNK) m = ACHUNK;
    for (int i = tid; i < m; i += 256) {
        int src, dst; load_edge(ei, yei, e1, e2, e0 + i, src, dst);
        atomicAdd(&hist[dst >> BSH], 1);
    }
    __syncthreads();
    for (int i = tid; i < NB; i += 256)
        if (hist[i]) atomicAdd(&btot[i], hist[i]);
}

// ---------------- scan buckets (NB <= 1024, one block) ----------------
__global__ __launch_bounds__(1024) void scan_buckets_k(const int* __restrict__ btot,
                                                       int* __restrict__ bstart, int* __restrict__ bcursor, int NB) {
    __shared__ int sd[1024];
    int tid = threadIdx.x;
    int v = (tid < NB) ? btot[tid] : 0;
    sd[tid] = v;
    __syncthreads();
    int val = v;
    for (int off = 1; off < 1024; off <<= 1) {
        int t = (tid >= off) ? sd[tid - off] : 0;
        __syncthreads();
        val += t;
        sd[tid] = val;
        __syncthreads();
    }
    if (tid < NB) { int ex = val - v; bstart[tid] = ex; bcursor[tid] = ex; }
}

// ---------------- pass A-scatter: LDS multisplit, coalesced copy-out ----------------
__global__ __launch_bounds__(256) void passA_scatter_k(const int* __restrict__ ei, const int* __restrict__ yei,
                                                       int e1, int e2, int* __restrict__ bcursor,
                                                       unsigned* __restrict__ bucketed, int NB) {
    __shared__ int hist[1024];            // counts, then repurposed as cursors
    __shared__ int scanex[1024];          // exclusive scan of counts
    __shared__ int segb[1024];            // global segment base per bucket
    __shared__ int sd[256];
    __shared__ unsigned stage[ACHUNK];    // packed (src<<7)|ldst
    __shared__ unsigned short bof[ACHUNK];
    int tid = threadIdx.x;
    int E = e1 + e2;
    int e0 = blockIdx.x * ACHUNK;
    int m = E - e0; if (m > ACHUNK) m = ACHUNK;
    for (int i = tid; i < 1024; i += 256) hist[i] = 0;
    __syncthreads();
    for (int i = tid; i < m; i += 256) {
        int src, dst; load_edge(ei, yei, e1, e2, e0 + i, src, dst);
        atomicAdd(&hist[dst >> BSH], 1);
    }
    __syncthreads();
    // scan 1024 bins with 256 threads (4 bins/thread)
    int b4 = tid * 4;
    int c0 = hist[b4], c1 = hist[b4 + 1], c2 = hist[b4 + 2], c3 = hist[b4 + 3];
    int tot4 = c0 + c1 + c2 + c3;
    sd[tid] = tot4;
    __syncthreads();
    int val = tot4;
    for (int off = 1; off < 256; off <<= 1) {
        int t = (tid >= off) ? sd[tid - off] : 0;
        __syncthreads();
        val += t;
        sd[tid] = val;
        __syncthreads();
    }
    int eb = val - tot4;
    scanex[b4] = eb; scanex[b4 + 1] = eb + c0; scanex[b4 + 2] = eb + c0 + c1; scanex[b4 + 3] = eb + c0 + c1 + c2;
    __syncthreads();
    // reserve global segments
    for (int b = tid; b < NB; b += 256)
        segb[b] = hist[b] ? atomicAdd(&bcursor[b], hist[b]) : 0;
    __syncthreads();
    // repurpose hist as LDS cursors
    for (int b = tid; b < 1024; b += 256) hist[b] = scanex[b];
    __syncthreads();
    for (int i = tid; i < m; i += 256) {
        int src, dst; load_edge(ei, yei, e1, e2, e0 + i, src, dst);
        int b = dst >> BSH;
        int pos = atomicAdd(&hist[b], 1);
        stage[pos] = ((unsigned)src << BSH) | (unsigned)(dst & (BW - 1));
        bof[pos] = (unsigned short)b;
    }
    __syncthreads();
    for (int i = tid; i < m; i += 256) {
        int b = bof[i];
        bucketed[segb[b] + (i - scanex[b])] = stage[i];
    }
}

// ---------------- pass B1: per-bucket degree -> dinv ----------------
__global__ __launch_bounds__(256) void passB1_k(const unsigned* __restrict__ bucketed,
                                                const int* __restrict__ bstart, const int* __restrict__ btot,
                                                float* __restrict__ dinv, int n) {
    __shared__ int cnt[BW];
    int tid = threadIdx.x;
    int b = blockIdx.x;
    int s = bstart[b], tot = btot[b];
    if (tid < BW) cnt[tid] = 0;
    __syncthreads();
    for (int i = tid; i < tot; i += 256)
        atomicAdd(&cnt[bucketed[s + i] & (BW - 1)], 1);
    __syncthreads();
    if (tid < BW) {
        int node = (b << BSH) + tid;
        if (node < n) dinv[node] = rsqrtf((float)cnt[tid] + 1.0f);
    }
}

// ---------------- pass B2: rebuild local CSR in LDS + fused gather + output ----------------
__global__ __launch_bounds__(256) void passB2_k(const unsigned* __restrict__ bucketed,
                                                const int* __restrict__ bstart, const int* __restrict__ btot,
                                                const float* __restrict__ dinv,
                                                const __hip_bfloat16* __restrict__ h,
                                                const float* __restrict__ bias,
                                                float* __restrict__ out, int n) {
    __shared__ int cnt[BW], rowoff[BW], cur[BW];
    __shared__ unsigned stage[BCAP];
    int tid = threadIdx.x;
    int b = blockIdx.x;
    int s = bstart[b], tot = btot[b];
    int dst0 = b << BSH;
    int g = tid >> 5, j = tid & 31;
    float bj = bias[j];
    float acc[16];
#pragma unroll
    for (int q = 0; q < 16; ++q) acc[q] = 0.0f;

    for (int c0 = 0; c0 < tot; c0 += BCAP) {
        int m = tot - c0; if (m > BCAP) m = BCAP;
        if (tid < BW) cnt[tid] = 0;
        __syncthreads();
        for (int i = tid; i < m; i += 256)
            atomicAdd(&cnt[bucketed[s + c0 + i] & (BW - 1)], 1);
        __syncthreads();
        // exclusive scan of cnt[128] (all threads hit the syncs)
        if (tid < BW) rowoff[tid] = cnt[tid];
        __syncthreads();
        for (int off = 1; off < BW; off <<= 1) {
            int t = 0;
            if (tid < BW && tid >= off) t = rowoff[tid - off];
            __syncthreads();
            if (tid < BW) rowoff[tid] += t;
            __syncthreads();
        }
        if (tid < BW) { int ex = rowoff[tid] - cnt[tid]; rowoff[tid] = ex; cur[tid] = ex; }
        __syncthreads();
        for (int i = tid; i < m; i += 256) {
            unsigned e = bucketed[s + c0 + i];
            int ld = e & (BW - 1);
            int p = atomicAdd(&cur[ld], 1);
            stage[p] = e >> BSH;   // src
        }
        __syncthreads();
        // gather for this chunk's sub-CSR
#pragma unroll 1
        for (int q = 0; q < 16; ++q) {
            int ld = g + q * 8;
            int rs = rowoff[ld], re = rs + cnt[ld];
            for (int base = rs; base < re; base += 32) {
                int mm = re - base; if (mm > 32) mm = 32;
                int   myS = (j < mm) ? (int)stage[base + j] : 0;
                float myW = (j < mm) ? dinv[myS] : 0.0f;
                if (mm == 32) {
#pragma unroll
                    for (int t = 0; t < 32; ++t) {
                        int   sl = __shfl(myS, t, 32);
                        float w  = __shfl(myW, t, 32);
                        acc[q] += __bfloat162float(h[(size_t)sl * LATD + j]) * w;
                    }
                } else {
#pragma unroll 4
                    for (int t = 0; t < mm; ++t) {
                        int   sl = __shfl(myS, t, 32);
                        float w  = __shfl(myW, t, 32);
                        acc[q] += __bfloat162float(h[(size_t)sl * LATD + j]) * w;
                    }
                }
            }
        }
        __syncthreads();  // before next chunk reuses cnt/stage
    }
    // epilogue: self-loop + bias + normalized neighbor sum
#pragma unroll 1
    for (int q = 0; q < 16; ++q) {
        int ld = g + q * 8;
        int node = dst0 + ld;
        if (node < n) {
            float dv = dinv[node];
            float self = __bfloat162float(h[(size_t)node * LATD + j]);
            out[(size_t)node * LATD + j] = self * dv * dv + bj + acc[q] * dv;
        }
    }
}

// ---------------- fallback path (atomic scatter) ----------------
__global__ void count_k(const int* __restrict__ ei, const int* __restrict__ yei,
                        int* __restrict__ cnt, int e1, int e2) {
    int e = blockIdx.x * 256 + threadIdx.x;
    if (e >= e1 + e2) return;
    int src, dst; load_edge(ei, yei, e1, e2, e, src, dst);
    atomicAdd(&cnt[dst], 1);
}

__global__ void dinv_k(const int* __restrict__ cnt, float* __restrict__ dinv, int n) {
    int i = blockIdx.x * 256 + threadIdx.x;
    if (i < n) dinv[i] = rsqrtf((float)cnt[i] + 1.0f);
}

__global__ void selfbias_k(const float* __restrict__ dinv, const __hip_bfloat16* __restrict__ h,
                           const float* __restrict__ b, float* __restrict__ out, int total) {
    int idx = blockIdx.x * 256 + threadIdx.x;
    if (idx >= total) return;
    int i = idx >> 5, j = idx & 31;
    float d = dinv[i];
    out[idx] = __bfloat162float(h[idx]) * d * d + b[j];
}

__global__ void scatter_atomic_k(const int* __restrict__ ei, const int* __restrict__ yei,
                                 const float* __restrict__ dinv, const __hip_bfloat16* __restrict__ h,
                                 float* __restrict__ out, int e1, int e2) {
    int idx = blockIdx.x * 256 + threadIdx.x;
    int e = idx >> 5;
    if (e >= e1 + e2) return;
    int j = idx & 31;
    int src, dst; load_edge(ei, yei, e1, e2, e, src, dst);
    float norm = dinv[src] * dinv[dst];
    atomicAdd(&out[(size_t)dst * LATD + j], __bfloat162float(h[(size_t)src * LATD + j]) * norm);
}

static inline size_t aln(size_t x) { return (x + 255) & ~(size_t)255; }

extern "C" void kernel_launch(void* const* d_in, const int* in_sizes, int n_in,
                              void* d_out, int out_size, void* d_ws, size_t ws_size,
                              hipStream_t stream) {
    const float* x  = (const float*)d_in[0];
    const int* ei   = (const int*)d_in[1];
    const int* yei  = (const int*)d_in[2];
    const float* W  = (const float*)d_in[3];
    const float* b  = (const float*)d_in[4];
    float* out = (float*)d_out;

    int n  = in_sizes[0] / INCH;
    int e1 = in_sizes[1] / 2;
    int e2 = in_sizes[2] / 2;
    int E  = e1 + e2;
    int NB = (n + BW - 1) >> BSH;

    char* p = (char*)d_ws;
    size_t off = 0;
    float* dinv = (float*)(p + off);            off += aln((size_t)n * 4);
    __hip_bfloat16* h = (__hip_bfloat16*)(p + off); off += aln((size_t)n * LATD * 2);
    unsigned* bucketed = (unsigned*)(p + off);  size_t bucketed_off = off; off += aln((size_t)E * 4);
    int* btot    = (int*)(p + off); off += aln(1024 * 4);
    int* bstart  = (int*)(p + off); off += aln(1024 * 4);
    int* bcursor = (int*)(p + off); off += aln(1024 * 4);
    bool fast_ok = (off <= ws_size) && (NB <= 1024);

    gemm_tile_k<<<(n + 63) / 64, 128, 0, stream>>>(x, W, h, n);

    if (fast_ok) {
        int ablocks = (E + ACHUNK - 1) / ACHUNK;
        zero_i32_k<<<(NB + 255) / 256, 256, 0, stream>>>(btot, NB);
        bucket_count_k<<<ablocks, 256, 0, stream>>>(ei, yei, e1, e2, btot, NB);
        scan_buckets_k<<<1, 1024, 0, stream>>>(btot, bstart, bcursor, NB);
        passA_scatter_k<<<ablocks, 256, 0, stream>>>(ei, yei, e1, e2, bcursor, bucketed, NB);
        passB1_k<<<NB, 256, 0, stream>>>(bucketed, bstart, btot, dinv, n);
        passB2_k<<<NB, 256, 0, stream>>>(bucketed, bstart, btot, dinv, h, b, out, n);
    } else {
        int* cnt = (int*)(p + bucketed_off);  // reuse bucketed region
        zero_i32_k<<<(n + 255) / 256, 256, 0, stream>>>(cnt, n);
        count_k<<<(E + 255) / 256, 256, 0, stream>>>(ei, yei, cnt, e1, e2);
        dinv_k<<<(n + 255) / 256, 256, 0, stream>>>(cnt, dinv, n);
        selfbias_k<<<(out_size + 255) / 256, 256, 0, stream>>>(dinv, h, b, out, out_size);
        scatter_atomic_k<<<((size_t)E * LATD + 255) / 256, 256, 0, stream>>>(ei, yei, dinv, h, out, e1, e2);
    }
}